// Round 8
// baseline (581.541 us; speedup 1.0000x reference)
//
#include <hip/hip_runtime.h>
#include <hip/hip_bf16.h>

#define N_NODES 20000
#define N_EDGES 320000
#define F_IN 512
#define HEADS 8
#define DH 64
#define KPAD 64   // padded CSR stride; P(Poisson(16) > 64) ~ 1e-19, drop-guarded

typedef _Float16 f16;
typedef __attribute__((ext_vector_type(8))) _Float16 half8;
typedef __attribute__((ext_vector_type(4))) _Float16 half4v;
typedef __attribute__((ext_vector_type(2))) _Float16 half2v;
typedef __attribute__((ext_vector_type(4))) float f32x4;

// async global->LDS, 16B per lane; lds base must be wave-uniform (HW adds lane*16)
__device__ __forceinline__ void async_copy16(void* lds_base, const void* g) {
  __builtin_amdgcn_global_load_lds(
      (const __attribute__((address_space(1))) unsigned int*)g,
      (__attribute__((address_space(3))) unsigned int*)lds_base, 16, 0, 0);
}

// ---------------- fused prologue: cast_x | cast_w | wa-projection | padded-CSR scatter ----
#define CX_BLOCKS 2500    // grid-stride x4: 2500*256*4*4 = 20000*512
#define CW_BLOCKS 128
#define WA_BLOCKS 16      // 16 folded projection rows: Wt rows 1024..1039
#define SCAT_BLOCKS 1250

__global__ __launch_bounds__(256) void prologue_kernel(
    const float* __restrict__ x, const float* __restrict__ We,
    const float* __restrict__ Wr, const float* __restrict__ a,
    const int* __restrict__ ei,
    f16* __restrict__ xh, f16* __restrict__ Wt,
    int* __restrict__ cnt, int* __restrict__ csr)
{
  __shared__ f16 tile[64 * 65];
  const int b = blockIdx.x;
  if (b < CX_BLOCKS) {
    int base = (b * 256 + threadIdx.x) * 4;
    #pragma unroll
    for (int rep = 0; rep < 4; ++rep) {
      int i = base + rep * (CX_BLOCKS * 256 * 4);
      float4 v = *(const float4*)&x[i];
      half4v o;
      o[0] = (f16)v.x; o[1] = (f16)v.y; o[2] = (f16)v.z; o[3] = (f16)v.w;
      *(half4v*)&xh[i] = o;
    }
  } else if (b < CX_BLOCKS + CW_BLOCKS) {
    const int bb = b - CX_BLOCKS;       // (mat, h, ktile)
    const int kt = (bb & 7) * 64;
    const int h = (bb >> 3) & 7;
    const int mat = bb >> 6;
    const float* __restrict__ W = (mat ? Wr : We) + (size_t)h * F_IN * DH;
    #pragma unroll
    for (int r = 0; r < 16; ++r) {
      int idx = r * 256 + threadIdx.x;
      int k = idx >> 6, d = idx & 63;
      tile[d * 65 + k] = (f16)W[(size_t)(kt + k) * DH + d];
    }
    __syncthreads();
    f16* __restrict__ Wo = Wt + (size_t)(mat * 8 + h) * 64 * F_IN;
    #pragma unroll
    for (int r = 0; r < 16; ++r) {
      int idx = r * 256 + threadIdx.x;
      int d = idx >> 6, k = idx & 63;
      Wo[(size_t)d * F_IN + kt + k] = tile[d * 65 + k];
    }
  } else if (b < CX_BLOCKS + CW_BLOCKS + WA_BLOCKS) {
    // wa row j: j<8 -> ssrc head j = We[h].a_src - Wr[h].a_dif
    //           j>=8 -> sdst head j-8 = We[h].a_dst + Wr[h].a_dif
    const int j = b - CX_BLOCKS - CW_BLOCKS;  // 0..15
    const int h = j & 7, sel = j >> 3;
    const float* __restrict__ ae = a + h * 320 + (sel ? 64 : 0);
    const float* __restrict__ ad = a + h * 320 + 128;
    const float sgn = sel ? 1.f : -1.f;
    #pragma unroll
    for (int rep = 0; rep < 2; ++rep) {
      int k = rep * 256 + threadIdx.x;
      const float* __restrict__ we = We + ((size_t)h * F_IN + k) * DH;
      const float* __restrict__ wr = Wr + ((size_t)h * F_IN + k) * DH;
      float s = 0.f;
      #pragma unroll
      for (int d = 0; d < DH; ++d)
        s = fmaf(we[d], ae[d], fmaf(sgn * wr[d], ad[d], s));
      Wt[(size_t)(1024 + j) * F_IN + k] = (f16)s;
    }
  } else {
    int e = (b - CX_BLOCKS - CW_BLOCKS - WA_BLOCKS) * 256 + threadIdx.x;
    if (e < N_EDGES) {
      int s = ei[e];
      int t = ei[N_EDGES + e];
      int pos = atomicAdd(&cnt[s], 1);
      if (pos < KPAD) csr[s * KPAD + pos] = t;   // guard: never taken for this graph
    }
  }
}

// ---------------- fused h_e/h_r GEMM: 128x128, f16 MFMA, double-buffered ----------------
// Output hef[n][1024]: cols 0-511 = h_e (8 heads x 64), 512-1023 = h_r.
// 9th c_tile produces ssrc/sdst directly from acc[i][0] of the cb==16 wave.
// PROBE round 8: GREP=12 in-kernel repeats (idempotent; acc re-zeroed per rep,
// smem reuse barrier-protected) so gemm becomes the LARGEST dispatch and surfaces
// in the rocprof top-5 with full counters. Divide its dur by 12 for true G.
#define GBM 128
#define GBN 128
#define GBK 64
#define MT_TOTAL 157
#define MT_PER_GRP 20
#define NCT 9              // 8 hef col-tiles + 1 projection tile
#define NKT (F_IN / GBK)   // 8
#define TSTR 72            // epilogue transpose row stride (f16): 144B, 16B-aligned
#define GREP 12            // PROBE multiplier

__global__ __launch_bounds__(256) void gemm_mfma(
    const f16* __restrict__ xh, const f16* __restrict__ Wt,
    f16* __restrict__ hef,
    float* __restrict__ ssrc, float* __restrict__ sdst)
{
  const int b = blockIdx.x;
  const int g = b & 7;               // XCD group = m-group for L2 locality
  const int j = b >> 3;
  const int mg = j / NCT;
  const int m_tile = g * MT_PER_GRP + mg;
  const int c_tile = j - mg * NCT;
  if (m_tile >= MT_TOTAL) return;

  __shared__ f16 smem[32768];        // As[2][8192] | Bs[2][8192]; reused by epilogue
  f16* __restrict__ As = smem;              // As + buf*8192
  f16* __restrict__ Bs = smem + 16384;      // Bs + buf*8192
  const int tid = threadIdx.x;
  const int m0 = m_tile * GBM;
  const int n0 = c_tile * GBN;               // c_tile==8 -> rows 1024..1151 of Wt
  const int wv = tid >> 6, lane = tid & 63, quad = lane >> 4, l16 = lane & 15;
  const int wm = (wv >> 1) * 64;
  const int wn = (wv & 1) * 64;
  const int lrow = lane >> 3;
  const int gc = (lane & 7) ^ (lrow & 7);   // swizzled source chunk

  auto stage = [&](int kt, int buf) {
    #pragma unroll
    for (int s = 0; s < 4; ++s) {
      int seg = wv * 4 + s;
      int row = seg * 8 + lrow;
      async_copy16(&As[buf * 8192 + seg * 512],
                   &xh[(size_t)(m0 + row) * F_IN + kt + gc * 8]);  // OOB rows read ws garbage; masked at store
      async_copy16(&Bs[buf * 8192 + seg * 512],
                   &Wt[(size_t)(n0 + row) * F_IN + kt + gc * 8]);
    }
  };

  const int cb = c_tile * 2 + (wv & 1);  // global 64-col block
  const int mat = cb >> 3, h = cb & 7;   // mat 0/1 = hef halves; mat==2 = projection tile

  for (int rep = 0; rep < GREP; ++rep) {
    f32x4 acc[4][4] = {};

    stage(0, 0);
    __syncthreads();
    for (int it = 0; it < NKT; ++it) {
      if (it + 1 < NKT) stage((it + 1) * GBK, (it + 1) & 1);
      const f16* __restrict__ Ab = &As[(it & 1) * 8192];
      const f16* __restrict__ Bb = &Bs[(it & 1) * 8192];
      #pragma unroll
      for (int ks = 0; ks < 2; ++ks) {
        half8 af[4], bf4[4];
        const int ch = ((ks << 2) + quad) ^ (l16 & 7);
        #pragma unroll
        for (int i = 0; i < 4; ++i)
          af[i] = *(const half8*)&Ab[(wm + i * 16 + l16) * GBK + ch * 8];
        #pragma unroll
        for (int jj = 0; jj < 4; ++jj)
          bf4[jj] = *(const half8*)&Bb[(wn + jj * 16 + l16) * GBK + ch * 8];
        #pragma unroll
        for (int i = 0; i < 4; ++i)
          #pragma unroll
          for (int jj = 0; jj < 4; ++jj)
            acc[i][jj] = __builtin_amdgcn_mfma_f32_16x16x32_f16(af[i], bf4[jj], acc[i][jj], 0, 0, 0);
      }
      __syncthreads();
    }

    if (mat < 2) {
      // ---- vectorized C-store via per-wave private LDS transpose ----
      f16* __restrict__ tb = smem + wv * (64 * TSTR);   // 64 rows x 72 f16 = 9216B/wave
      #pragma unroll
      for (int i = 0; i < 4; ++i)
        #pragma unroll
        for (int jj = 0; jj < 4; ++jj)
          #pragma unroll
          for (int r = 0; r < 4; ++r)
            tb[(i * 16 + quad * 4 + r) * TSTR + jj * 16 + l16] = (f16)acc[i][jj][r];
      const int rrow = lane >> 3;     // 0..7
      const int rseg = lane & 7;      // 0..7 (16B segment)
      #pragma unroll
      for (int g2 = 0; g2 < 8; ++g2) {
        int row = g2 * 8 + rrow;
        half8 vv = *(const half8*)&tb[row * TSTR + rseg * 8];
        int m = m0 + wm + row;
        if (m < N_NODES)
          *(half8*)&hef[(size_t)m * 1024 + mat * 512 + h * DH + rseg * 8] = vv;
      }
    } else if (cb == 16) {
      // projection wave: acc[i][0] cols l16 = B rows 1024+l16
      //   l16 0..7 -> ssrc head l16 ; l16 8..15 -> sdst head l16-8  (f32, exact)
      #pragma unroll
      for (int i = 0; i < 4; ++i) {
        #pragma unroll
        for (int r = 0; r < 4; ++r) {
          int m = m0 + wm + i * 16 + quad * 4 + r;
          if (m < N_NODES) {
            float v = acc[i][0][r];
            if (l16 < 8) ssrc[(size_t)m * HEADS + l16] = v;
            else         sdst[(size_t)m * HEADS + (l16 - 8)] = v;
          }
        }
      }
    }
    __syncthreads();   // protect smem (tb overlaps As/Bs) before next rep's stage
  }
}

// ---------------- fused attention: one wave per node, packed-f16 + v_dot2 ----------------
// lane = h*8 + oct; lane covers dims d = oct*8..oct*8+7 of head h.
// a_dif term pre-folded into ssrc/sdst (wa columns in gemm) -> per edge only abs+prd dots,
// in TWO independent fdot2 chains (serial depth 4). Re-fused to one dispatch (round-5 form).
__global__ __launch_bounds__(256) void attn_kernel(
    const f16* __restrict__ hef, const float* __restrict__ a,
    const float* __restrict__ ssrc, const float* __restrict__ sdst,
    const int* __restrict__ cnt, const int* __restrict__ csr,
    float* __restrict__ out)
{
  const int wv = threadIdx.x >> 6;
  const int n = blockIdx.x * 4 + wv;       // 5000 * 4 = 20000 exact
  const int lane = threadIdx.x & 63;
  const int h = lane >> 3;
  const int d0 = (lane & 7) * 8;
  const int deg = min(cnt[n], KPAD);
  const int beg = n * KPAD, end = beg + deg;

  const half8 hrn = *(const half8*)&hef[(size_t)n * 1024 + lane * 8 + 512];
  half2v aabs2[4], aprd2[4];
  const int ab = h * 320;
  #pragma unroll
  for (int c = 0; c < 4; ++c) {
    aabs2[c][0] = (f16)a[ab + 192 + d0 + 2 * c];
    aabs2[c][1] = (f16)a[ab + 192 + d0 + 2 * c + 1];
    aprd2[c][0] = (f16)a[ab + 256 + d0 + 2 * c];
    aprd2[c][1] = (f16)a[ab + 256 + d0 + 2 * c + 1];
  }
  const float sbase = ssrc[(size_t)n * HEADS + h];

  float denom = 0.f;
  float acc[8] = {};

  auto edge = [&](half8 he8, half8 hr8, float sd) {
    half8 df = hr8 - hrn;                 // v_pk_sub_f16
    uint4 u = __builtin_bit_cast(uint4, df);
    u.x &= 0x7FFF7FFFu; u.y &= 0x7FFF7FFFu; u.z &= 0x7FFF7FFFu; u.w &= 0x7FFF7FFFu;
    half8 ad = __builtin_bit_cast(half8, u);   // |diff|
    half8 pr = hr8 * hrn;                 // v_pk_mul_f16
    float va = 0.f, vb = 0.f;             // two independent chains
    #pragma unroll
    for (int c = 0; c < 4; ++c) {
      half2v ad2 = {ad[2 * c], ad[2 * c + 1]};
      half2v pr2 = {pr[2 * c], pr[2 * c + 1]};
      va = __builtin_amdgcn_fdot2(ad2, aabs2[c], va, false);
      vb = __builtin_amdgcn_fdot2(pr2, aprd2[c], vb, false);
    }
    float v = va + vb;
    v += __shfl_xor(v, 1);
    v += __shfl_xor(v, 2);
    v += __shfl_xor(v, 4);                // head-group (8 lanes) sum
    float sc = sbase + sd + v;
    sc = fmaxf(sc, 0.2f * sc);            // leaky_relu
    float ex = __expf(sc);                // scores bounded; no max-shift (verified r1-r7)
    denom += ex;
    #pragma unroll
    for (int jj = 0; jj < 8; ++jj) acc[jj] = fmaf(ex, (float)he8[jj], acc[jj]);
  };

  int i = beg;
  for (; i + 2 <= end; i += 2) {
    int t0 = csr[i], t1 = csr[i + 1];
    size_t b0 = (size_t)t0 * 1024 + lane * 8;
    size_t b1 = (size_t)t1 * 1024 + lane * 8;
    half8 e0 = *(const half8*)&hef[b0];
    half8 r0 = *(const half8*)&hef[b0 + 512];
    half8 e1 = *(const half8*)&hef[b1];
    half8 r1 = *(const half8*)&hef[b1 + 512];
    float s0 = sdst[(size_t)t0 * HEADS + h];
    float s1 = sdst[(size_t)t1 * HEADS + h];
    edge(e0, r0, s0);
    edge(e1, r1, s1);
  }
  if (i < end) {
    int t = csr[i];
    size_t b0 = (size_t)t * 1024 + lane * 8;
    half8 e0 = *(const half8*)&hef[b0];
    half8 r0 = *(const half8*)&hef[b0 + 512];
    edge(e0, r0, sdst[(size_t)t * HEADS + h]);
  }

  float inv = 1.f / (denom + 1e-16f);
  float4 o0, o1;
  o0.x = acc[0] * inv; o0.y = acc[1] * inv; o0.z = acc[2] * inv; o0.w = acc[3] * inv;
  o1.x = acc[4] * inv; o1.y = acc[5] * inv; o1.z = acc[6] * inv; o1.w = acc[7] * inv;
  *(float4*)&out[(size_t)n * 512 + lane * 8] = o0;
  *(float4*)&out[(size_t)n * 512 + lane * 8 + 4] = o1;
}

// ---------------- launch ----------------
extern "C" void kernel_launch(void* const* d_in, const int* in_sizes, int n_in,
                              void* d_out, int out_size, void* d_ws, size_t ws_size,
                              hipStream_t stream) {
  const float* x  = (const float*)d_in[0];
  const int*   ei = (const int*)d_in[1];
  const float* We = (const float*)d_in[2];
  const float* Wr = (const float*)d_in[3];
  const float* a  = (const float*)d_in[4];
  float* out = (float*)d_out;

  char* ws = (char*)d_ws;
  size_t p = 0;
  auto alloc = [&](size_t bytes) {
    void* r = ws + p;
    p = (p + bytes + 255) & ~(size_t)255;
    return r;
  };
  f16* xh  = (f16*)alloc(sizeof(f16) * (size_t)N_NODES * F_IN);
  f16* Wt  = (f16*)alloc(sizeof(f16) * (size_t)1152 * F_IN);   // 1024 W rows + 16 wa + 112 pad (read, unused)
  f16* hef = (f16*)alloc(sizeof(f16) * (size_t)N_NODES * 1024);
  float* ssrc = (float*)alloc(sizeof(float) * (size_t)N_NODES * HEADS);
  float* sdst = (float*)alloc(sizeof(float) * (size_t)N_NODES * HEADS);
  int* cnt = (int*)alloc(sizeof(int) * N_NODES);
  int* csr = (int*)alloc(sizeof(int) * (size_t)N_NODES * KPAD);

  hipMemsetAsync(cnt, 0, sizeof(int) * N_NODES, stream);

  prologue_kernel<<<CX_BLOCKS + CW_BLOCKS + WA_BLOCKS + SCAT_BLOCKS, 256, 0, stream>>>(
      x, We, Wr, a, ei, xh, Wt, cnt, csr);

  gemm_mfma<<<8 * MT_PER_GRP * NCT, 256, 0, stream>>>(xh, Wt, hef, ssrc, sdst);

  attn_kernel<<<N_NODES / 4, 256, 0, stream>>>(hef, a, ssrc, sdst, cnt, csr, out);
}

// Round 9
// 235.437 us; speedup vs baseline: 2.4700x; 2.4700x over previous
//
#include <hip/hip_runtime.h>
#include <hip/hip_bf16.h>

#define N_NODES 20000
#define N_EDGES 320000
#define F_IN 512
#define HEADS 8
#define DH 64
#define KPAD 64   // padded CSR stride; P(Poisson(16) > 64) ~ 1e-19, drop-guarded

typedef _Float16 f16;
typedef __attribute__((ext_vector_type(8))) _Float16 half8;
typedef __attribute__((ext_vector_type(4))) _Float16 half4v;
typedef __attribute__((ext_vector_type(2))) _Float16 half2v;
typedef __attribute__((ext_vector_type(4))) float f32x4;

// async global->LDS, 16B per lane; lds base must be wave-uniform (HW adds lane*16)
__device__ __forceinline__ void async_copy16(void* lds_base, const void* g) {
  __builtin_amdgcn_global_load_lds(
      (const __attribute__((address_space(1))) unsigned int*)g,
      (__attribute__((address_space(3))) unsigned int*)lds_base, 16, 0, 0);
}

// ---------------- fused prologue: cast_x | cast_w | wa-projection ----------------
// (CSR scatter moved into the gemm grid tail for overlap with MFMA blocks.)
#define CX_BLOCKS 2500    // grid-stride x4: 2500*256*4*4 = 20000*512
#define CW_BLOCKS 128
#define WA_BLOCKS 16      // 16 folded projection rows: Wt rows 1024..1039

__global__ __launch_bounds__(256) void prologue_kernel(
    const float* __restrict__ x, const float* __restrict__ We,
    const float* __restrict__ Wr, const float* __restrict__ a,
    f16* __restrict__ xh, f16* __restrict__ Wt)
{
  __shared__ f16 tile[64 * 65];
  const int b = blockIdx.x;
  if (b < CX_BLOCKS) {
    int base = (b * 256 + threadIdx.x) * 4;
    #pragma unroll
    for (int rep = 0; rep < 4; ++rep) {
      int i = base + rep * (CX_BLOCKS * 256 * 4);
      float4 v = *(const float4*)&x[i];
      half4v o;
      o[0] = (f16)v.x; o[1] = (f16)v.y; o[2] = (f16)v.z; o[3] = (f16)v.w;
      *(half4v*)&xh[i] = o;
    }
  } else if (b < CX_BLOCKS + CW_BLOCKS) {
    const int bb = b - CX_BLOCKS;       // (mat, h, ktile)
    const int kt = (bb & 7) * 64;
    const int h = (bb >> 3) & 7;
    const int mat = bb >> 6;
    const float* __restrict__ W = (mat ? Wr : We) + (size_t)h * F_IN * DH;
    #pragma unroll
    for (int r = 0; r < 16; ++r) {
      int idx = r * 256 + threadIdx.x;
      int k = idx >> 6, d = idx & 63;
      tile[d * 65 + k] = (f16)W[(size_t)(kt + k) * DH + d];
    }
    __syncthreads();
    f16* __restrict__ Wo = Wt + (size_t)(mat * 8 + h) * 64 * F_IN;
    #pragma unroll
    for (int r = 0; r < 16; ++r) {
      int idx = r * 256 + threadIdx.x;
      int d = idx >> 6, k = idx & 63;
      Wo[(size_t)d * F_IN + kt + k] = tile[d * 65 + k];
    }
  } else {
    // wa row j: j<8 -> ssrc head j = We[h].a_src - Wr[h].a_dif
    //           j>=8 -> sdst head j-8 = We[h].a_dst + Wr[h].a_dif
    const int j = b - CX_BLOCKS - CW_BLOCKS;  // 0..15
    const int h = j & 7, sel = j >> 3;
    const float* __restrict__ ae = a + h * 320 + (sel ? 64 : 0);
    const float* __restrict__ ad = a + h * 320 + 128;
    const float sgn = sel ? 1.f : -1.f;
    #pragma unroll
    for (int rep = 0; rep < 2; ++rep) {
      int k = rep * 256 + threadIdx.x;
      const float* __restrict__ we = We + ((size_t)h * F_IN + k) * DH;
      const float* __restrict__ wr = Wr + ((size_t)h * F_IN + k) * DH;
      float s = 0.f;
      #pragma unroll
      for (int d = 0; d < DH; ++d)
        s = fmaf(we[d], ae[d], fmaf(sgn * wr[d], ad[d], s));
      Wt[(size_t)(1024 + j) * F_IN + k] = (f16)s;
    }
  }
}

// ---------------- fused h_e/h_r GEMM + concurrent CSR scatter ----------------
// Output hef[n][1024]: cols 0-511 = h_e (8 heads x 64), 512-1023 = h_r.
// 9th c_tile produces ssrc/sdst directly from acc[i][0] of the cb==16 wave.
// Blocks >= GEMM_GRID are CSR-scatter blocks (ei -> cnt/csr): independent of
// gemm inputs, they pack into the gemm's idle issue slots (occupancy 10.7%)
// and retire-tail instead of serializing in the prologue.
#define GBM 128
#define GBN 128
#define GBK 64
#define MT_TOTAL 157
#define MT_PER_GRP 20
#define NCT 9              // 8 hef col-tiles + 1 projection tile
#define NKT (F_IN / GBK)   // 8
#define TSTR 72            // epilogue transpose row stride (f16): 144B, 16B-aligned
#define GEMM_GRID (8 * MT_PER_GRP * NCT)   // 1440
#define SCAT_BLOCKS 1250

__global__ __launch_bounds__(256) void gemm_mfma(
    const f16* __restrict__ xh, const f16* __restrict__ Wt,
    f16* __restrict__ hef,
    float* __restrict__ ssrc, float* __restrict__ sdst,
    const int* __restrict__ ei, int* __restrict__ cnt, int* __restrict__ csr)
{
  const int b = blockIdx.x;
  if (b >= GEMM_GRID) {
    // ---- concurrent padded-CSR scatter tail ----
    int e = (b - GEMM_GRID) * 256 + threadIdx.x;
    if (e < N_EDGES) {
      int s = ei[e];
      int t = ei[N_EDGES + e];
      int pos = atomicAdd(&cnt[s], 1);
      if (pos < KPAD) csr[s * KPAD + pos] = t;   // guard: never taken for this graph
    }
    return;
  }

  const int g = b & 7;               // XCD group = m-group for L2 locality
  const int j = b >> 3;
  const int mg = j / NCT;
  const int m_tile = g * MT_PER_GRP + mg;
  const int c_tile = j - mg * NCT;
  if (m_tile >= MT_TOTAL) return;

  __shared__ f16 smem[32768];        // As[2][8192] | Bs[2][8192]; reused by epilogue
  f16* __restrict__ As = smem;              // As + buf*8192
  f16* __restrict__ Bs = smem + 16384;      // Bs + buf*8192
  const int tid = threadIdx.x;
  const int m0 = m_tile * GBM;
  const int n0 = c_tile * GBN;               // c_tile==8 -> rows 1024..1151 of Wt
  const int wv = tid >> 6, lane = tid & 63, quad = lane >> 4, l16 = lane & 15;
  const int wm = (wv >> 1) * 64;
  const int wn = (wv & 1) * 64;
  const int lrow = lane >> 3;
  const int gc = (lane & 7) ^ (lrow & 7);   // swizzled source chunk

  f32x4 acc[4][4] = {};

  auto stage = [&](int kt, int buf) {
    #pragma unroll
    for (int s = 0; s < 4; ++s) {
      int seg = wv * 4 + s;
      int row = seg * 8 + lrow;
      async_copy16(&As[buf * 8192 + seg * 512],
                   &xh[(size_t)(m0 + row) * F_IN + kt + gc * 8]);  // OOB rows read ws garbage; masked at store
      async_copy16(&Bs[buf * 8192 + seg * 512],
                   &Wt[(size_t)(n0 + row) * F_IN + kt + gc * 8]);
    }
  };

  stage(0, 0);
  __syncthreads();
  for (int it = 0; it < NKT; ++it) {
    if (it + 1 < NKT) stage((it + 1) * GBK, (it + 1) & 1);
    const f16* __restrict__ Ab = &As[(it & 1) * 8192];
    const f16* __restrict__ Bb = &Bs[(it & 1) * 8192];
    #pragma unroll
    for (int ks = 0; ks < 2; ++ks) {
      half8 af[4], bf4[4];
      const int ch = ((ks << 2) + quad) ^ (l16 & 7);
      #pragma unroll
      for (int i = 0; i < 4; ++i)
        af[i] = *(const half8*)&Ab[(wm + i * 16 + l16) * GBK + ch * 8];
      #pragma unroll
      for (int jj = 0; jj < 4; ++jj)
        bf4[jj] = *(const half8*)&Bb[(wn + jj * 16 + l16) * GBK + ch * 8];
      #pragma unroll
      for (int i = 0; i < 4; ++i)
        #pragma unroll
        for (int jj = 0; jj < 4; ++jj)
          acc[i][jj] = __builtin_amdgcn_mfma_f32_16x16x32_f16(af[i], bf4[jj], acc[i][jj], 0, 0, 0);
    }
    __syncthreads();
  }

  const int cb = c_tile * 2 + (wv & 1);  // global 64-col block
  const int mat = cb >> 3, h = cb & 7;   // mat 0/1 = hef halves; mat==2 = projection tile

  if (mat < 2) {
    // ---- vectorized C-store via per-wave private LDS transpose (no barrier needed:
    // last main-loop __syncthreads() freed LDS; each wave touches only its own region,
    // ds_write -> ds_read ordering within a wave is enforced by lgkmcnt) ----
    f16* __restrict__ tb = smem + wv * (64 * TSTR);   // 64 rows x 72 f16 = 9216B/wave
    #pragma unroll
    for (int i = 0; i < 4; ++i)
      #pragma unroll
      for (int jj = 0; jj < 4; ++jj)
        #pragma unroll
        for (int r = 0; r < 4; ++r)
          tb[(i * 16 + quad * 4 + r) * TSTR + jj * 16 + l16] = (f16)acc[i][jj][r];
    const int rrow = lane >> 3;     // 0..7
    const int rseg = lane & 7;      // 0..7 (16B segment)
    #pragma unroll
    for (int g2 = 0; g2 < 8; ++g2) {
      int row = g2 * 8 + rrow;
      half8 vv = *(const half8*)&tb[row * TSTR + rseg * 8];
      int m = m0 + wm + row;
      if (m < N_NODES)
        *(half8*)&hef[(size_t)m * 1024 + mat * 512 + h * DH + rseg * 8] = vv;
    }
  } else if (cb == 16) {
    // projection wave: acc[i][0] cols l16 = B rows 1024+l16
    //   l16 0..7  -> ssrc head l16 ; l16 8..15 -> sdst head l16-8  (f32, exact)
    #pragma unroll
    for (int i = 0; i < 4; ++i) {
      #pragma unroll
      for (int r = 0; r < 4; ++r) {
        int m = m0 + wm + i * 16 + quad * 4 + r;
        if (m < N_NODES) {
          float v = acc[i][0][r];
          if (l16 < 8) ssrc[(size_t)m * HEADS + l16] = v;
          else         sdst[(size_t)m * HEADS + (l16 - 8)] = v;
        }
      }
    }
  }
}

// ---------------- fused attention: one wave per node, packed-f16 + v_dot2 ----------------
// lane = h*8 + oct; lane covers dims d = oct*8..oct*8+7 of head h.
// a_dif term pre-folded into ssrc/sdst (wa columns in gemm) -> per edge only abs+prd dots,
// in TWO independent fdot2 chains (serial depth 4).
__global__ __launch_bounds__(256) void attn_kernel(
    const f16* __restrict__ hef, const float* __restrict__ a,
    const float* __restrict__ ssrc, const float* __restrict__ sdst,
    const int* __restrict__ cnt, const int* __restrict__ csr,
    float* __restrict__ out)
{
  const int wv = threadIdx.x >> 6;
  const int n = blockIdx.x * 4 + wv;       // 5000 * 4 = 20000 exact
  const int lane = threadIdx.x & 63;
  const int h = lane >> 3;
  const int d0 = (lane & 7) * 8;
  const int deg = min(cnt[n], KPAD);
  const int beg = n * KPAD, end = beg + deg;

  const half8 hrn = *(const half8*)&hef[(size_t)n * 1024 + lane * 8 + 512];
  half2v aabs2[4], aprd2[4];
  const int ab = h * 320;
  #pragma unroll
  for (int c = 0; c < 4; ++c) {
    aabs2[c][0] = (f16)a[ab + 192 + d0 + 2 * c];
    aabs2[c][1] = (f16)a[ab + 192 + d0 + 2 * c + 1];
    aprd2[c][0] = (f16)a[ab + 256 + d0 + 2 * c];
    aprd2[c][1] = (f16)a[ab + 256 + d0 + 2 * c + 1];
  }
  const float sbase = ssrc[(size_t)n * HEADS + h];

  float denom = 0.f;
  float acc[8] = {};

  auto edge = [&](half8 he8, half8 hr8, float sd) {
    half8 df = hr8 - hrn;                 // v_pk_sub_f16
    uint4 u = __builtin_bit_cast(uint4, df);
    u.x &= 0x7FFF7FFFu; u.y &= 0x7FFF7FFFu; u.z &= 0x7FFF7FFFu; u.w &= 0x7FFF7FFFu;
    half8 ad = __builtin_bit_cast(half8, u);   // |diff|
    half8 pr = hr8 * hrn;                 // v_pk_mul_f16
    float va = 0.f, vb = 0.f;             // two independent chains
    #pragma unroll
    for (int c = 0; c < 4; ++c) {
      half2v ad2 = {ad[2 * c], ad[2 * c + 1]};
      half2v pr2 = {pr[2 * c], pr[2 * c + 1]};
      va = __builtin_amdgcn_fdot2(ad2, aabs2[c], va, false);
      vb = __builtin_amdgcn_fdot2(pr2, aprd2[c], vb, false);
    }
    float v = va + vb;
    v += __shfl_xor(v, 1);
    v += __shfl_xor(v, 2);
    v += __shfl_xor(v, 4);                // head-group (8 lanes) sum
    float sc = sbase + sd + v;
    sc = fmaxf(sc, 0.2f * sc);            // leaky_relu
    float ex = __expf(sc);                // scores bounded; no max-shift (verified r1-r7)
    denom += ex;
    #pragma unroll
    for (int jj = 0; jj < 8; ++jj) acc[jj] = fmaf(ex, (float)he8[jj], acc[jj]);
  };

  int i = beg;
  for (; i + 2 <= end; i += 2) {
    int t0 = csr[i], t1 = csr[i + 1];
    size_t b0 = (size_t)t0 * 1024 + lane * 8;
    size_t b1 = (size_t)t1 * 1024 + lane * 8;
    half8 e0 = *(const half8*)&hef[b0];
    half8 r0 = *(const half8*)&hef[b0 + 512];
    half8 e1 = *(const half8*)&hef[b1];
    half8 r1 = *(const half8*)&hef[b1 + 512];
    float s0 = sdst[(size_t)t0 * HEADS + h];
    float s1 = sdst[(size_t)t1 * HEADS + h];
    edge(e0, r0, s0);
    edge(e1, r1, s1);
  }
  if (i < end) {
    int t = csr[i];
    size_t b0 = (size_t)t * 1024 + lane * 8;
    half8 e0 = *(const half8*)&hef[b0];
    half8 r0 = *(const half8*)&hef[b0 + 512];
    edge(e0, r0, sdst[(size_t)t * HEADS + h]);
  }

  float inv = 1.f / (denom + 1e-16f);
  float4 o0, o1;
  o0.x = acc[0] * inv; o0.y = acc[1] * inv; o0.z = acc[2] * inv; o0.w = acc[3] * inv;
  o1.x = acc[4] * inv; o1.y = acc[5] * inv; o1.z = acc[6] * inv; o1.w = acc[7] * inv;
  *(float4*)&out[(size_t)n * 512 + lane * 8] = o0;
  *(float4*)&out[(size_t)n * 512 + lane * 8 + 4] = o1;
}

// ---------------- launch ----------------
extern "C" void kernel_launch(void* const* d_in, const int* in_sizes, int n_in,
                              void* d_out, int out_size, void* d_ws, size_t ws_size,
                              hipStream_t stream) {
  const float* x  = (const float*)d_in[0];
  const int*   ei = (const int*)d_in[1];
  const float* We = (const float*)d_in[2];
  const float* Wr = (const float*)d_in[3];
  const float* a  = (const float*)d_in[4];
  float* out = (float*)d_out;

  char* ws = (char*)d_ws;
  size_t p = 0;
  auto alloc = [&](size_t bytes) {
    void* r = ws + p;
    p = (p + bytes + 255) & ~(size_t)255;
    return r;
  };
  f16* xh  = (f16*)alloc(sizeof(f16) * (size_t)N_NODES * F_IN);
  f16* Wt  = (f16*)alloc(sizeof(f16) * (size_t)1152 * F_IN);   // 1024 W rows + 16 wa + 112 pad (read, unused)
  f16* hef = (f16*)alloc(sizeof(f16) * (size_t)N_NODES * 1024);
  float* ssrc = (float*)alloc(sizeof(float) * (size_t)N_NODES * HEADS);
  float* sdst = (float*)alloc(sizeof(float) * (size_t)N_NODES * HEADS);
  int* cnt = (int*)alloc(sizeof(int) * N_NODES);
  int* csr = (int*)alloc(sizeof(int) * (size_t)N_NODES * KPAD);

  hipMemsetAsync(cnt, 0, sizeof(int) * N_NODES, stream);

  prologue_kernel<<<CX_BLOCKS + CW_BLOCKS + WA_BLOCKS, 256, 0, stream>>>(
      x, We, Wr, a, xh, Wt);

  gemm_mfma<<<GEMM_GRID + SCAT_BLOCKS, 256, 0, stream>>>(
      xh, Wt, hef, ssrc, sdst, ei, cnt, csr);

  attn_kernel<<<N_NODES / 4, 256, 0, stream>>>(hef, a, ssrc, sdst, cnt, csr, out);
}